// Round 15
// baseline (1018.819 us; speedup 1.0000x reference)
//
#include <hip/hip_runtime.h>
#include <hip/hip_bf16.h>

#define H 256
#define NACC 100000
#define NTX  300000
#define NE   600000
#define NM   300000

typedef unsigned short u16;
typedef unsigned int u32;
typedef __bf16 bf16x8 __attribute__((ext_vector_type(8)));
typedef float f32x4 __attribute__((ext_vector_type(4)));
typedef unsigned int u32x4 __attribute__((ext_vector_type(4)));

__device__ __forceinline__ float bf2f(u32 u) {
    union { u32 i; float f; } v; v.i = u << 16; return v.f;
}
__device__ __forceinline__ u16 f2bf(float f) {
    union { float f; u32 i; } v; v.f = f;
    u32 r = v.i + 0x7FFFu + ((v.i >> 16) & 1u);
    return (u16)(r >> 16);
}
__device__ __forceinline__ u32 pk2(float a, float b) {
    return (u32)f2bf(a) | ((u32)f2bf(b) << 16);
}
__device__ __forceinline__ void acc8(float* s, uint4 v) {
    s[0] += bf2f(v.x & 0xffff); s[1] += bf2f(v.x >> 16);
    s[2] += bf2f(v.y & 0xffff); s[3] += bf2f(v.y >> 16);
    s[4] += bf2f(v.z & 0xffff); s[5] += bf2f(v.z >> 16);
    s[6] += bf2f(v.w & 0xffff); s[7] += bf2f(v.w >> 16);
}

// ---------------- zero fill (no hipMemsetAsync: breaks graph capture) ----------------
__global__ void fillz_kernel(u32* __restrict__ p, long long n) {
    long long i = (long long)blockIdx.x * blockDim.x + threadIdx.x;
    long long st = (long long)gridDim.x * blockDim.x;
    for (; i < n; i += st) p[i] = 0u;
}

// ---------------- weight prep ----------------
__global__ void wcat_kernel(const float* __restrict__ Wl, const float* __restrict__ Wr,
                            u16* __restrict__ dst) {
    int c = blockIdx.x, t = threadIdx.x;
    dst[(size_t)c * 512 + t]       = f2bf(Wl[(size_t)c * 256 + t]);
    dst[(size_t)c * 512 + 256 + t] = f2bf(Wr[(size_t)c * 256 + t]);
}
// MFMA fragment-ordered concat, 3 configs in one launch (blockIdx.y = cfg)
__global__ void wcat_frag3_kernel(const float* __restrict__ Wl0, const float* __restrict__ Wr0,
                                  const float* __restrict__ Wl1, const float* __restrict__ Wr1,
                                  const float* __restrict__ Wl2, const float* __restrict__ Wr2,
                                  u16* __restrict__ d0, u16* __restrict__ d1, u16* __restrict__ d2) {
    int cfg = blockIdx.y;
    const float* Wl = (cfg == 0) ? Wl0 : (cfg == 1) ? Wl1 : Wl2;
    const float* Wr = (cfg == 0) ? Wr0 : (cfg == 1) ? Wr1 : Wr2;
    u16* dst = (cfg == 0) ? d0 : (cfg == 1) ? d1 : d2;
    int c = blockIdx.x, k = threadIdx.x;   // 256 x 512
    float v = (k < 256) ? Wl[(size_t)c * 256 + k] : Wr[(size_t)c * 256 + (k - 256)];
    int kstep = k >> 5, kg = (k & 31) >> 3, j = k & 7;
    dst[(size_t)((kstep * 16 + (c >> 4)) * 64 + kg * 16 + (c & 15)) * 8 + j] = f2bf(v);
}
__global__ void w1frag_kernel(const float* __restrict__ W1, u16* __restrict__ dst) {
    int c = blockIdx.x;
    for (int k = threadIdx.x; k < 544; k += 256) {
        float v = W1[(size_t)c * 544 + k];
        int kstep = k >> 5, kg = (k & 31) >> 3, j = k & 7;
        dst[(size_t)((kstep * 16 + (c >> 4)) * 64 + kg * 16 + (c & 15)) * 8 + j] = f2bf(v);
    }
}
// both projection-weight tables in one launch (blockIdx.y)
__global__ void wproj2_kernel(const float* __restrict__ Wa, const float* __restrict__ Wt,
                              u16* __restrict__ dA, u16* __restrict__ dT) {
    int c = blockIdx.x, t = threadIdx.x;   // 32 threads
    if (blockIdx.y == 0) dA[(size_t)c * 32 + t] = (t < 16) ? f2bf(Wa[(size_t)c * 16 + t]) : (u16)0;
    else                 dT[(size_t)c * 32 + t] = f2bf(Wt[(size_t)c * 32 + t]);
}
// all 3 BN-fold configs in one launch (blockIdx.x = cfg)
__global__ void bnprep3_kernel(const float* __restrict__ bl_ta, const float* __restrict__ bl_at,
                               const float* __restrict__ g_, const float* __restrict__ be_,
                               const float* __restrict__ m_, const float* __restrict__ v_,
                               float* __restrict__ S, float* __restrict__ B) {
    int cfg = blockIdx.x, c = threadIdx.x;
    const float* bl = (cfg == 0) ? bl_ta : (cfg == 1) ? bl_at : (bl_ta + 256);
    int po = (cfg == 2) ? 256 : 0;
    float s = g_[po + c] * rsqrtf(v_[po + c] + 1e-5f);
    S[cfg * 256 + c] = s;
    B[cfg * 256 + c] = (bl[c] - m_[po + c]) * s + be_[po + c];
}

// ---------------- MFMA projection (validated round 7; nt input stream) ------
template <int KK>
__launch_bounds__(256)
__global__ void proj_mfma(const float* __restrict__ x, const u16* __restrict__ Wb,
                          const float* __restrict__ b, u16* __restrict__ out, int N) {
    __shared__ __align__(16) u16 Af[8][64][8];
    __shared__ __align__(16) u16 Bf[16][64][8];
    int tid = threadIdx.x;
    int w = tid >> 6, lane = tid & 63;
    int row0 = blockIdx.x * 128;
    {
        int r = tid >> 1, h = tid & 1;
        int gr = row0 + r;
        int rt = r >> 4, rr = r & 15;
        uint4 p0 = make_uint4(0, 0, 0, 0), p1 = p0;
        if (gr < N && (KK == 32 || h == 0)) {
            const f32x4* xp = (const f32x4*)(x + (size_t)gr * KK + h * 16);
            f32x4 f0 = __builtin_nontemporal_load(xp);
            f32x4 f1 = __builtin_nontemporal_load(xp + 1);
            f32x4 f2 = __builtin_nontemporal_load(xp + 2);
            f32x4 f3 = __builtin_nontemporal_load(xp + 3);
            p0 = make_uint4(pk2(f0[0], f0[1]), pk2(f0[2], f0[3]), pk2(f1[0], f1[1]), pk2(f1[2], f1[3]));
            p1 = make_uint4(pk2(f2[0], f2[1]), pk2(f2[2], f2[3]), pk2(f3[0], f3[1]), pk2(f3[2], f3[3]));
        }
        int kg0 = 2 * h;
        *(uint4*)(&Af[rt][(kg0 * 16 + rr) ^ (kg0 << 2)][0]) = p0;
        *(uint4*)(&Af[rt][((kg0 + 1) * 16 + rr) ^ ((kg0 + 1) << 2)][0]) = p1;
    }
    {
        const u16* wp = Wb + (size_t)tid * 32;
#pragma unroll
        for (int q = 0; q < 4; ++q) {
            uint4 wv = *(const uint4*)(wp + q * 8);
            *(uint4*)(&Bf[tid >> 4][q * 16 + (tid & 15)][0]) = wv;
        }
    }
    __syncthreads();
    int arslot = lane ^ ((lane >> 4) << 2);
    f32x4 acc[8][4];
#pragma unroll
    for (int rt = 0; rt < 8; ++rt) {
        bf16x8 afr = *(const bf16x8*)(&Af[rt][arslot][0]);
#pragma unroll
        for (int ct = 0; ct < 4; ++ct) {
            bf16x8 bfr = *(const bf16x8*)(&Bf[w * 4 + ct][lane][0]);
            acc[rt][ct] = __builtin_amdgcn_mfma_f32_16x16x32_bf16(
                afr, bfr, (f32x4){0.f, 0.f, 0.f, 0.f}, 0, 0, 0);
        }
    }
    int rb = (lane >> 4) * 4, cc = lane & 15;
#pragma unroll
    for (int ct = 0; ct < 4; ++ct) {
        int cg = (w * 4 + ct) * 16 + cc;
        float bv = b[cg];
#pragma unroll
        for (int rt = 0; rt < 8; ++rt)
#pragma unroll
            for (int q = 0; q < 4; ++q) {
                int r = row0 + rt * 16 + rb + q;
                if (r < N)
                    out[(size_t)r * H + cg] = f2bf(fmaxf(acc[rt][ct][q] + bv, 0.0f));
            }
    }
}

// ---------------- CSR build (merged across both edge directions) ----------------
__global__ void count2_kernel(const int* __restrict__ dstS, const int* __restrict__ dstR, int E,
                              int* __restrict__ cntT, int* __restrict__ cntA) {
    int e = blockIdx.x * blockDim.x + threadIdx.x;
    if (e >= E) return;
    if (blockIdx.y == 0) atomicAdd(&cntT[dstS[e]], 1);
    else                 atomicAdd(&cntA[dstR[e]], 1);
}
__global__ void scan1_kernel(const int* __restrict__ cnt, int N,
                             int* __restrict__ loc, int* __restrict__ bsum) {
    __shared__ int sh[256];
    int b = blockIdx.x, t = threadIdx.x;
    int base = b * 1024 + t * 4;
    int v0 = (base + 0 < N) ? cnt[base + 0] : 0;
    int v1 = (base + 1 < N) ? cnt[base + 1] : 0;
    int v2 = (base + 2 < N) ? cnt[base + 2] : 0;
    int v3 = (base + 3 < N) ? cnt[base + 3] : 0;
    int s = v0 + v1 + v2 + v3;
    sh[t] = s;
    __syncthreads();
    for (int o = 1; o < 256; o <<= 1) {
        int y = (t >= o) ? sh[t - o] : 0;
        __syncthreads();
        sh[t] += y;
        __syncthreads();
    }
    int run = sh[t] - s;
    if (base + 0 < N) loc[base + 0] = run; run += v0;
    if (base + 1 < N) loc[base + 1] = run; run += v1;
    if (base + 2 < N) loc[base + 2] = run; run += v2;
    if (base + 3 < N) loc[base + 3] = run;
    if (t == 0) bsum[b] = sh[255];
}
__global__ void scan2_kernel(int* __restrict__ bsum, int nb) {
    __shared__ int sh[1024];
    int t = threadIdx.x;
    int v = (t < nb) ? bsum[t] : 0;
    sh[t] = v;
    __syncthreads();
    for (int o = 1; o < 1024; o <<= 1) {
        int y = (t >= o) ? sh[t - o] : 0;
        __syncthreads();
        sh[t] += y;
        __syncthreads();
    }
    if (t < nb) bsum[t] = sh[t] - v;
}
__global__ void scan3_kernel(int* __restrict__ ptr, const int* __restrict__ bsum,
                             int N, int total) {
    int i = blockIdx.x * blockDim.x + threadIdx.x;
    if (i < N) ptr[i] += bsum[i >> 10];
    else if (i == N) ptr[N] = total;
}
__global__ void fillcsr2_kernel(const int* __restrict__ srcS, const int* __restrict__ dstS,
                                const int* __restrict__ srcR, const int* __restrict__ dstR, int E,
                                const int* __restrict__ ptrT, int* __restrict__ curT, int* __restrict__ permS,
                                const int* __restrict__ ptrA, int* __restrict__ curA, int* __restrict__ permR) {
    int e = blockIdx.x * blockDim.x + threadIdx.x;
    if (e >= E) return;
    if (blockIdx.y == 0) {
        int d = dstS[e];
        permS[ptrT[d] + atomicAdd(&curT[d], 1)] = srcS[e];
    } else {
        int d = dstR[e];
        permR[ptrA[d] + atomicAdd(&curA[d], 1)] = srcR[e];
    }
}

// ---------------- gather-mean (kept for sliced fallback) ------------
template <int WS>
__launch_bounds__(256)
__global__ void gmean_kernel(const u16* __restrict__ feat, int fstride,
                             const int* __restrict__ ptr, const int* __restrict__ perm,
                             u16* __restrict__ out, int ostride, int c0,
                             int rows, int lo) {
    constexpr int LPD = WS / 4;
    constexpr int DPB = 256 / LPD;
    int g = threadIdx.x / LPD;
    int ln = threadIdx.x % LPD;
    int w = blockIdx.x * DPB + g;
    if (w >= rows) return;
    int d = lo + w;
    int e0 = ptr[d], e1 = ptr[d + 1];
    float a0 = 0.f, a1 = 0.f, a2 = 0.f, a3 = 0.f;
    for (int e = e0; e < e1; ++e) {
        int s = perm[e];
        uint2 v = *(const uint2*)(feat + (size_t)s * fstride + (ln << 2));
        a0 += bf2f(v.x & 0xffff); a1 += bf2f(v.x >> 16);
        a2 += bf2f(v.y & 0xffff); a3 += bf2f(v.y >> 16);
    }
    int deg = e1 - e0;
    float sc = (deg > 0) ? (1.0f / (float)deg) : 0.0f;
    uint2 pk;
    pk.x = pk2(a0 * sc, a1 * sc);
    pk.y = pk2(a2 * sc, a3 * sc);
    *(uint2*)(out + (size_t)w * ostride + c0 + (ln << 2)) = pk;
}

// ---------------- proj2 (kept for sliced fallback) ----------------
template <int K, int NC>
__launch_bounds__(256)
__global__ void proj2_kernel(const float* __restrict__ x, const float* __restrict__ W,
                             const float* __restrict__ b, u16* __restrict__ out,
                             int N, int c0, int ost) {
    __shared__ float xs[128][K + 4];
    constexpr int NG = 512 / NC;
    constexpr int RPT = 128 / NG;
    int tid = threadIdx.x;
    int row0 = blockIdx.x * 128;
    constexpr int NF4 = 128 * K / 4;
    for (int f = tid; f < NF4; f += 256) {
        int r = f / (K / 4), kq = (f % (K / 4)) * 4;
        int gr = row0 + r;
        float4 v = (gr < N) ? *(const float4*)(x + (size_t)gr * K + kq)
                            : make_float4(0.f, 0.f, 0.f, 0.f);
        *(float4*)&xs[r][kq] = v;
    }
    int lt2 = (tid % (NC / 2)) * 2;
    int g = tid / (NC / 2);
    float wa[K], wb[K];
    const float* wpa = W + (size_t)(c0 + lt2) * K;
#pragma unroll
    for (int k = 0; k < K; k += 4) {
        float4 va = *(const float4*)(wpa + k);
        float4 vb = *(const float4*)(wpa + K + k);
        wa[k] = va.x; wa[k + 1] = va.y; wa[k + 2] = va.z; wa[k + 3] = va.w;
        wb[k] = vb.x; wb[k + 1] = vb.y; wb[k + 2] = vb.z; wb[k + 3] = vb.w;
    }
    float b0 = b[c0 + lt2], b1 = b[c0 + lt2 + 1];
    __syncthreads();
#pragma unroll
    for (int rr = 0; rr < RPT; ++rr) {
        int r = g * RPT + rr;
        int gr = row0 + r;
        float a0 = b0, a1 = b1;
#pragma unroll
        for (int k = 0; k < K; k += 4) {
            float4 xv = *(const float4*)&xs[r][k];
            a0 += xv.x * wa[k] + xv.y * wa[k + 1] + xv.z * wa[k + 2] + xv.w * wa[k + 3];
            a1 += xv.x * wb[k] + xv.y * wb[k + 1] + xv.z * wb[k + 2] + xv.w * wb[k + 3];
        }
        if (gr < N) {
            u32 pk = (u32)f2bf(fmaxf(a0, 0.f)) | ((u32)f2bf(fmaxf(a1, 0.f)) << 16);
            *(u32*)(out + (size_t)gr * ost + lt2) = pk;
        }
    }
}

// ---------------- fused gather-mean + MFMA combine, v6 ----------------
// = round-11-validated v4 (unroll2, plain bounds, 48 VGPR) + NON-TEMPORAL xd
// stream loads so the read-once xd stream does not evict the L3-resident
// gather table (featG). Stores stay cached (output is next kernel's table).
__launch_bounds__(512)
__global__ void combine_gather(const u16* __restrict__ featG, const int* __restrict__ ptr,
                               const int* __restrict__ perm, const u16* __restrict__ xd,
                               const u16* __restrict__ WcF,
                               const float* __restrict__ bnS, const float* __restrict__ bnB,
                               u16* __restrict__ outF, int rows) {
    __shared__ __align__(16) u16 Am[8][4][64][8];   // 32 KB: mean half, fragment-ordered
    int tid = threadIdx.x;
    int w = tid >> 6, lane = tid & 63;
    int row0 = blockIdx.x * 64;

    // ---- phase 1: gather-mean, 8 threads per row (32 cols each), unroll2 ----
    {
        int r = tid >> 3, g = tid & 7;      // r 0..63, colgroup g 0..7
        int grow = row0 + r;
        float s[32];
#pragma unroll
        for (int i = 0; i < 32; ++i) s[i] = 0.0f;
        float inv = 0.0f;
        if (grow < rows) {
            int e0 = ptr[grow], e1 = ptr[grow + 1];
            int dg = e1 - e0;
            inv = (dg > 0) ? 1.0f / (float)dg : 0.0f;
            int e = e0;
            for (; e + 1 < e1; e += 2) {
                int n0 = perm[e], n1 = perm[e + 1];
                const u16* p0 = featG + (size_t)n0 * H + g * 32;
                const u16* p1 = featG + (size_t)n1 * H + g * 32;
#pragma unroll
                for (int q = 0; q < 4; ++q) {
                    uint4 v0 = *(const uint4*)(p0 + q * 8);
                    uint4 v1 = *(const uint4*)(p1 + q * 8);
                    acc8(s + q * 8, v0);
                    acc8(s + q * 8, v1);
                }
            }
            if (e < e1) {
                int n0 = perm[e];
                const u16* p0 = featG + (size_t)n0 * H + g * 32;
#pragma unroll
                for (int q = 0; q < 4; ++q)
                    acc8(s + q * 8, *(const uint4*)(p0 + q * 8));
            }
        }
        int rt = r >> 4, rr = r & 15;
#pragma unroll
        for (int q = 0; q < 4; ++q) {
            int kgg = g * 4 + q;                 // global kgroup 0..31
            int kbs = kgg >> 2, akg = kgg & 3;   // kb-step, in-step group
            uint4 pv;
            pv.x = pk2(s[q * 8 + 0] * inv, s[q * 8 + 1] * inv);
            pv.y = pk2(s[q * 8 + 2] * inv, s[q * 8 + 3] * inv);
            pv.z = pk2(s[q * 8 + 4] * inv, s[q * 8 + 5] * inv);
            pv.w = pk2(s[q * 8 + 6] * inv, s[q * 8 + 7] * inv);
            *(uint4*)(&Am[kbs][rt][(akg * 16 + rr) ^ (akg << 2)][0]) = pv;
        }
    }
    __syncthreads();

    // ---- phase 2: barrier-free K-loop, wave w owns col-tiles w*2, w*2+1 ----
    int arslot = lane ^ ((lane >> 4) << 2);
    const u16* xrow[4];
#pragma unroll
    for (int rt = 0; rt < 4; ++rt) {
        int r = row0 + rt * 16 + (lane & 15);
        if (r > rows - 1) r = rows - 1;
        xrow[rt] = xd + (size_t)r * H + (lane >> 4) * 8;
    }
    const u16* wb = WcF + (size_t)lane * 8;

    f32x4 acc[4][2];
#pragma unroll
    for (int i = 0; i < 4; ++i) {
        acc[i][0] = (f32x4){0.f, 0.f, 0.f, 0.f};
        acc[i][1] = (f32x4){0.f, 0.f, 0.f, 0.f};
    }
#pragma unroll
    for (int ks = 0; ks < 8; ++ks) {        // kb 0..255: A from Am
        bf16x8 afr[4];
#pragma unroll
        for (int rt = 0; rt < 4; ++rt)
            afr[rt] = *(const bf16x8*)(&Am[ks][rt][arslot][0]);
#pragma unroll
        for (int j = 0; j < 2; ++j) {
            bf16x8 bfr = *(const bf16x8*)(wb + (size_t)(ks * 16 + w * 2 + j) * 512);
#pragma unroll
            for (int rt = 0; rt < 4; ++rt)
                acc[rt][j] = __builtin_amdgcn_mfma_f32_16x16x32_bf16(afr[rt], bfr, acc[rt][j], 0, 0, 0);
        }
    }
#pragma unroll
    for (int ks = 8; ks < 16; ++ks) {       // kb 256..511: A direct from xd (nt stream)
        bf16x8 afr[4];
#pragma unroll
        for (int rt = 0; rt < 4; ++rt) {
            u32x4 t = __builtin_nontemporal_load((const u32x4*)(xrow[rt] + (ks - 8) * 32));
            afr[rt] = *(const bf16x8*)&t;
        }
#pragma unroll
        for (int j = 0; j < 2; ++j) {
            bf16x8 bfr = *(const bf16x8*)(wb + (size_t)(ks * 16 + w * 2 + j) * 512);
#pragma unroll
            for (int rt = 0; rt < 4; ++rt)
                acc[rt][j] = __builtin_amdgcn_mfma_f32_16x16x32_bf16(afr[rt], bfr, acc[rt][j], 0, 0, 0);
        }
    }
    __syncthreads();   // in-place safety: all xd reads done before any store
    int rb = (lane >> 4) * 4, cc = lane & 15;
#pragma unroll
    for (int j = 0; j < 2; ++j) {
        int cg = (w * 2 + j) * 16 + cc;
        float s = bnS[cg], sh = bnB[cg];
#pragma unroll
        for (int rt = 0; rt < 4; ++rt)
#pragma unroll
            for (int q = 0; q < 4; ++q) {
                int r = row0 + rt * 16 + rb + q;
                if (r < rows)
                    outF[(size_t)r * H + cg] = f2bf(fmaxf(acc[rt][j][q] * s + sh, 0.0f));
            }
    }
}

// ---------------- MFMA SAGE combine (kept for sliced fallback, plain Wcat) ----------------
template <int COLS>
__launch_bounds__(256)
__global__ void combine_mfma(const u16* __restrict__ mean_, const u16* __restrict__ xd,
                             const u16* __restrict__ Wcat,
                             const float* __restrict__ bnS, const float* __restrict__ bnB,
                             u16* __restrict__ outF, int ostride, int out_c0,
                             int rows, int c0) {
    constexpr int NCT = COLS / 16;
    constexpr int CTW = NCT / 4;
    constexpr int PPT = (COLS * 4) / 256;
    __shared__ __align__(16) u16 Af[4][64][8];
    __shared__ __align__(16) u16 Bf[NCT][64][8];
    int tid = threadIdx.x;
    int w = tid >> 6, lane = tid & 63;
    int row0 = blockIdx.x * 64;
    int arow = tid >> 2, akg = tid & 3;
    bool arok = (row0 + arow) < rows;
    const u16* am = mean_ + (size_t)(row0 + arow) * H;
    const u16* ax = xd + (size_t)(row0 + arow) * H;
    int awslot = (akg * 16 + (arow & 15)) ^ (akg << 2);
    int arslot = lane ^ ((lane >> 4) << 2);
    int bc = tid % COLS;
    int bkg0 = (tid / COLS) * PPT;
    const u16* wp0 = Wcat + (size_t)(c0 + bc) * 512 + bkg0 * 8;

    f32x4 acc[4][CTW];
#pragma unroll
    for (int i = 0; i < 4; ++i)
#pragma unroll
        for (int j = 0; j < CTW; ++j) acc[i][j] = (f32x4){0.f, 0.f, 0.f, 0.f};

    for (int kb = 0; kb < 512; kb += 32) {
        uint4 av = make_uint4(0, 0, 0, 0);
        if (arok) {
            int kg = kb + akg * 8;
            av = (kg < 256) ? *(const uint4*)(am + kg) : *(const uint4*)(ax + (kg - 256));
        }
        *(uint4*)(&Af[arow >> 4][awslot][0]) = av;
#pragma unroll
        for (int q = 0; q < PPT; ++q) {
            uint4 wv = *(const uint4*)(wp0 + kb + q * 8);
            *(uint4*)(&Bf[bc >> 4][(bkg0 + q) * 16 + (bc & 15)][0]) = wv;
        }
        __syncthreads();
        bf16x8 afr[4];
#pragma unroll
        for (int rt = 0; rt < 4; ++rt)
            afr[rt] = *(const bf16x8*)(&Af[rt][arslot][0]);
#pragma unroll
        for (int ctl = 0; ctl < CTW; ++ctl) {
            bf16x8 b = *(const bf16x8*)(&Bf[w * CTW + ctl][lane][0]);
#pragma unroll
            for (int rt = 0; rt < 4; ++rt)
                acc[rt][ctl] = __builtin_amdgcn_mfma_f32_16x16x32_bf16(afr[rt], b, acc[rt][ctl], 0, 0, 0);
        }
        __syncthreads();
    }
    int rb = (lane >> 4) * 4;
    int ccol = lane & 15;
#pragma unroll
    for (int ctl = 0; ctl < CTW; ++ctl) {
        int clocal = (w * CTW + ctl) * 16 + ccol;
        int cg = c0 + clocal;
        float s = bnS[cg], sh = bnB[cg];
#pragma unroll
        for (int rt = 0; rt < 4; ++rt) {
#pragma unroll
            for (int q = 0; q < 4; ++q) {
                int r = row0 + rt * 16 + rb + q;
                if (r < rows)
                    outF[(size_t)r * ostride + out_c0 + clocal] = f2bf(fmaxf(acc[rt][ctl][q] * s + sh, 0.0f));
            }
        }
    }
}

// ---------------- MFMA edge-MLP head v4 (round-11 validated; nt tx_raw stream) ------
__launch_bounds__(512)
__global__ void mlp_mfma(const u16* __restrict__ accF, const int* __restrict__ sidx,
                         const int* __restrict__ ridx, const float* __restrict__ txr,
                         const u16* __restrict__ W1F, const float* __restrict__ b1,
                         const float* __restrict__ W2, const float* __restrict__ b2,
                         float* __restrict__ out, int M) {
    __shared__ __align__(16) u16 Af[4][64][8];
    __shared__ float red[8][64];
    int tid = threadIdx.x;
    int w = tid >> 6, lane = tid & 63;
    int row0 = blockIdx.x * 64;
    int sr = tid >> 3, sg = tid & 7;
    int grow = row0 + sr;
    int gcl = (grow > M - 1) ? (M - 1) : grow;
    const u16* srow_s = accF + (size_t)sidx[gcl] * H + sg * 4;
    const u16* srow_r = accF + (size_t)ridx[gcl] * H + sg * 4;
    const float* tp = txr + (size_t)gcl * 32 + sg * 4;
    int rt_s = sr >> 4, rr_s = sr & 15;
    int akg = sg >> 1, hh = (sg & 1) * 4;
    u16* wslot = &Af[rt_s][(akg * 16 + rr_s) ^ (akg << 2)][hh];

    auto stage_load = [&](int ks) -> uint2 {
        if (ks < 8)  return *(const uint2*)(srow_s + ks * 32);
        if (ks < 16) return *(const uint2*)(srow_r + (ks - 8) * 32);
        f32x4 f = __builtin_nontemporal_load((const f32x4*)tp);
        uint2 r;
        r.x = pk2(f[0], f[1]); r.y = pk2(f[2], f[3]);
        return r;
    };

    int arslot = lane ^ ((lane >> 4) << 2);
    const u16* wbs = W1F + (size_t)lane * 8;

    f32x4 acc[4][2];
#pragma unroll
    for (int i = 0; i < 4; ++i) {
        acc[i][0] = (f32x4){0.f, 0.f, 0.f, 0.f};
        acc[i][1] = (f32x4){0.f, 0.f, 0.f, 0.f};
    }

    uint2 reg = stage_load(0);
#pragma unroll
    for (int ks = 0; ks < 17; ++ks) {
        __syncthreads();
        *(uint2*)wslot = reg;
        __syncthreads();
        if (ks < 16) reg = stage_load(ks + 1);
        bf16x8 afr[4];
#pragma unroll
        for (int rt = 0; rt < 4; ++rt)
            afr[rt] = *(const bf16x8*)(&Af[rt][arslot][0]);
#pragma unroll
        for (int j = 0; j < 2; ++j) {
            bf16x8 bfr = *(const bf16x8*)(wbs + (size_t)(ks * 16 + w * 2 + j) * 512);
#pragma unroll
            for (int rt = 0; rt < 4; ++rt)
                acc[rt][j] = __builtin_amdgcn_mfma_f32_16x16x32_bf16(afr[rt], bfr, acc[rt][j], 0, 0, 0);
        }
    }
    float part[4][4];
#pragma unroll
    for (int rt = 0; rt < 4; ++rt)
#pragma unroll
        for (int q = 0; q < 4; ++q) part[rt][q] = 0.0f;
#pragma unroll
    for (int j = 0; j < 2; ++j) {
        int cg = (w * 2 + j) * 16 + (lane & 15);
        float b1v = b1[cg], w2v = W2[cg];
#pragma unroll
        for (int rt = 0; rt < 4; ++rt)
#pragma unroll
            for (int q = 0; q < 4; ++q)
                part[rt][q] += fmaxf(acc[rt][j][q] + b1v, 0.0f) * w2v;
    }
    int rb = (lane >> 4) * 4;
#pragma unroll
    for (int rt = 0; rt < 4; ++rt)
#pragma unroll
        for (int q = 0; q < 4; ++q) {
            float p = part[rt][q];
            p += __shfl_xor(p, 1);
            p += __shfl_xor(p, 2);
            p += __shfl_xor(p, 4);
            p += __shfl_xor(p, 8);
            if ((lane & 15) == 0) red[w][rt * 16 + rb + q] = p;
        }
    __syncthreads();
    if (tid < 64) {
        int r = row0 + tid;
        if (r < M)
            out[r] = red[0][tid] + red[1][tid] + red[2][tid] + red[3][tid]
                   + red[4][tid] + red[5][tid] + red[6][tid] + red[7][tid] + b2[0];
    }
}

// ---------------- host ----------------
static inline void fz(void* p, size_t bytes, hipStream_t s) {
    long long n = (long long)(bytes >> 2);
    int g = (int)(((n + 255) / 256 < 2048) ? (n + 255) / 256 : 2048);
    fillz_kernel<<<g, 256, 0, s>>>((u32*)p, n);
}
static inline size_t al256(size_t x) { return (x + 255) & ~(size_t)255; }

extern "C" void kernel_launch(void* const* d_in, const int* in_sizes, int n_in,
                              void* d_out, int out_size, void* d_ws, size_t ws_size,
                              hipStream_t stream) {
    const float* x_acc  = (const float*)d_in[0];
    const float* x_tx   = (const float*)d_in[1];
    const float* tx_raw = (const float*)d_in[2];
    const int* ei_sends = (const int*)d_in[3];
    const int* ei_recv  = (const int*)d_in[4];
    const int* sidx     = (const int*)d_in[5];
    const int* ridx     = (const int*)d_in[6];
    const float* W_acc  = (const float*)d_in[7];
    const float* b_acc  = (const float*)d_in[8];
    const float* W_tx   = (const float*)d_in[9];
    const float* b_tx   = (const float*)d_in[10];
    const float* Wl_at  = (const float*)d_in[11];
    const float* bl_at  = (const float*)d_in[12];
    const float* Wr_at  = (const float*)d_in[13];
    const float* Wl_ta  = (const float*)d_in[14];
    const float* bl_ta  = (const float*)d_in[15];
    const float* Wr_ta  = (const float*)d_in[16];
    const float* bng    = (const float*)d_in[17];
    const float* bnb    = (const float*)d_in[18];
    const float* bnm    = (const float*)d_in[19];
    const float* bnv    = (const float*)d_in[20];
    const float* W1     = (const float*)d_in[21];
    const float* b1     = (const float*)d_in[22];
    const float* W2     = (const float*)d_in[23];
    const float* b2     = (const float*)d_in[24];
    float* out = (float*)d_out;

    const size_t szFeatA = (size_t)NACC * H * 2;
    const size_t szFeatT = (size_t)NTX * H * 2;
    const size_t szCSR = al256((NTX + 1) * 4) + al256((NACC + 1) * 4) + al256(4096)
                       + al256((NTX + 1) * 4) + al256((NACC + 1) * 4)
                       + 2 * al256((size_t)NE * 4);
    const size_t szW = 3 * al256(256 * 512 * 2) + 3 * al256(16 * 16 * 64 * 8 * 2)
                     + al256(17 * 16 * 64 * 8 * 2)
                     + 2 * al256(3 * 256 * 4) + 2 * al256(256 * 32 * 2);

    size_t needF = szCSR + szW + 2 * al256(szFeatA) + al256(szFeatT) + 65536;
    auto needS = [&](int S, int CC) {
        return 3 * al256(szFeatA) + szCSR + szW + 2 * al256((size_t)CC * H * 2)
             + al256((size_t)NTX * (H / S) * 2) + 65536;
    };
    int plan, S = 2, CC = 16384;
    if (needF <= ws_size)                { plan = 0; }
    else if (needS(2, 16384) <= ws_size) { plan = 1; S = 2; CC = 16384; }
    else if (needS(4, 16384) <= ws_size) { plan = 1; S = 4; CC = 16384; }
    else                                 { plan = 1; S = 4; CC = 2048; }

    char* wsp = (char*)d_ws;
    size_t off = 0;
    auto alloc = [&](size_t bytes) -> void* {
        void* p = wsp + off;
        off = al256(off + bytes);
        return p;
    };
    // cntT and cntA adjacent so one fz covers both
    int* cntT  = (int*)alloc((NTX + 1) * 4);
    int* cntA  = (int*)alloc((NACC + 1) * 4);
    int* bsum  = (int*)alloc(4096);
    int* ptrT  = (int*)alloc((NTX + 1) * 4);
    int* ptrA  = (int*)alloc((NACC + 1) * 4);
    int* permS = (int*)alloc((size_t)NE * 4);
    int* permR = (int*)alloc((size_t)NE * 4);
    u16* Wc[3];
    Wc[0] = (u16*)alloc(256 * 512 * 2);
    Wc[1] = (u16*)alloc(256 * 512 * 2);
    Wc[2] = (u16*)alloc(256 * 512 * 2);
    u16* WcF[3];
    WcF[0] = (u16*)alloc(16 * 16 * 64 * 8 * 2);
    WcF[1] = (u16*)alloc(16 * 16 * 64 * 8 * 2);
    WcF[2] = (u16*)alloc(16 * 16 * 64 * 8 * 2);
    u16* W1F = (u16*)alloc(17 * 16 * 64 * 8 * 2);
    float* bnS = (float*)alloc(3 * 256 * 4);
    float* bnB = (float*)alloc(3 * 256 * 4);
    u16* WbA = (u16*)alloc(256 * 32 * 2);
    u16* WbT = (u16*)alloc(256 * 32 * 2);
    u16* A0f = (u16*)alloc(szFeatA);
    u16* A1f = (u16*)alloc(szFeatA);

    const size_t cntBytes = al256((NTX + 1) * 4) + al256((NACC + 1) * 4);

    // ---- weight prep (merged launches) ----
    wcat_frag3_kernel<<<dim3(256, 3), 512, 0, stream>>>(
        Wl_ta, Wr_ta, Wl_at, Wr_at, Wl_ta + H * H, Wr_ta + H * H, WcF[0], WcF[1], WcF[2]);
    w1frag_kernel<<<256, 256, 0, stream>>>(W1, W1F);
    wproj2_kernel<<<dim3(256, 2), 32, 0, stream>>>(W_acc, W_tx, WbA, WbT);
    bnprep3_kernel<<<3, 256, 0, stream>>>(bl_ta, bl_at, bng, bnb, bnm, bnv, bnS, bnB);

    // ---- CSR build, both directions merged ----
    const int EG = (NE + 255) / 256;
    const int nbT = (NTX + 1023) / 1024, nbA = (NACC + 1023) / 1024;
    fz(cntT, cntBytes, stream);
    count2_kernel<<<dim3(EG, 2), 256, 0, stream>>>(ei_sends + NE, ei_recv + NE, NE, cntT, cntA);
    scan1_kernel<<<nbT, 256, 0, stream>>>(cntT, NTX, ptrT, bsum);
    scan2_kernel<<<1, 1024, 0, stream>>>(bsum, nbT);
    scan3_kernel<<<(NTX + 256) / 256 + 1, 256, 0, stream>>>(ptrT, bsum, NTX, NE);
    scan1_kernel<<<nbA, 256, 0, stream>>>(cntA, NACC, ptrA, bsum);
    scan2_kernel<<<1, 1024, 0, stream>>>(bsum, nbA);
    scan3_kernel<<<(NACC + 256) / 256 + 1, 256, 0, stream>>>(ptrA, bsum, NACC, NE);
    fz(cntT, cntBytes, stream);
    fillcsr2_kernel<<<dim3(EG, 2), 256, 0, stream>>>(
        ei_sends, ei_sends + NE, ei_recv, ei_recv + NE, NE,
        ptrT, cntT, permS, ptrA, cntA, permR);

    // ---- acc projection (MFMA) ----
    proj_mfma<16><<<(NACC + 127) / 128, 256, 0, stream>>>(x_acc, WbA, b_acc, A0f, NACC);

    const int gA = (NACC + 63) / 64, gM = (NM + 63) / 64;

    if (plan == 0) {
        // ======== PLAN FULL (cg v6: unroll2 + nt streams) ========
        u16* T = (u16*)alloc(szFeatT);
        proj_mfma<32><<<(NTX + 127) / 128, 256, 0, stream>>>(x_tx, WbT, b_tx, T, NTX);
        // L0 acc: gather T0 over recv, root A0f -> A1f (must precede in-place T overwrite)
        combine_gather<<<gA, 512, 0, stream>>>(T, ptrA, permR, A0f, WcF[0], bnS, bnB, A1f, NACC);
        // L0 tx: gather A0f over sends, root T0 -> T1 in place
        combine_gather<<<(NTX + 63) / 64, 512, 0, stream>>>(A0f, ptrT, permS, T, WcF[1],
                                                            bnS + 256, bnB + 256, T, NTX);
        // L1 acc: gather T1 over recv, root A1f -> A2 (reuse A0f)
        combine_gather<<<gA, 512, 0, stream>>>(T, ptrA, permR, A1f, WcF[2],
                                               bnS + 512, bnB + 512, A0f, NACC);
        mlp_mfma<<<gM, 512, 0, stream>>>(A0f, sidx, ridx, tx_raw, W1F, b1, W2, b2, out, NM);
    } else {
        // ======== PLAN SLICED (validated fallback) ========
        wcat_kernel<<<256, 256, 0, stream>>>(Wl_ta, Wr_ta, Wc[0]);
        wcat_kernel<<<256, 256, 0, stream>>>(Wl_at, Wr_at, Wc[1]);
        wcat_kernel<<<256, 256, 0, stream>>>(Wl_ta + H * H, Wr_ta + H * H, Wc[2]);
        u16* meanbuf = (u16*)alloc(szFeatA);
        u16* T0c     = (u16*)alloc((size_t)CC * H * 2);
        u16* meanTc  = (u16*)alloc((size_t)CC * H * 2);
        const int WSL = H / S;
        u16* Tslice  = (u16*)alloc((size_t)NTX * WSL * 2);

        for (int s = 0; s < S; ++s) {
            int c0 = s * WSL;
            if (WSL == 128)
                proj2_kernel<32, 128><<<(NTX + 127) / 128, 256, 0, stream>>>(x_tx, W_tx, b_tx, Tslice, NTX, c0, WSL);
            else
                proj2_kernel<32, 64><<<(NTX + 127) / 128, 256, 0, stream>>>(x_tx, W_tx, b_tx, Tslice, NTX, c0, WSL);
            if (WSL == 128)
                gmean_kernel<128><<<(NACC + 7) / 8, 256, 0, stream>>>(Tslice, WSL, ptrA, permR, meanbuf, H, c0, NACC, 0);
            else
                gmean_kernel<64><<<(NACC + 15) / 16, 256, 0, stream>>>(Tslice, WSL, ptrA, permR, meanbuf, H, c0, NACC, 0);
        }
        combine_mfma<256><<<gA, 256, 0, stream>>>(meanbuf, A0f, Wc[0], bnS, bnB, A1f, H, 0, NACC, 0);
        for (int s = 0; s < S; ++s) {
            int c0 = s * WSL;
            for (int lo = 0; lo < NTX; lo += CC) {
                int cur = (NTX - lo < CC) ? (NTX - lo) : CC;
                proj2_kernel<32, 256><<<(cur + 127) / 128, 256, 0, stream>>>(x_tx + (size_t)lo * 32, W_tx, b_tx, T0c, cur, 0, H);
                gmean_kernel<256><<<(cur + 3) / 4, 256, 0, stream>>>(A0f, H, ptrT, permS, meanTc, H, 0, cur, lo);
                if (WSL == 128)
                    combine_mfma<128><<<(cur + 63) / 64, 256, 0, stream>>>(
                        meanTc, T0c, Wc[1], bnS + 256, bnB + 256,
                        Tslice + (size_t)lo * WSL, WSL, 0, cur, c0);
                else
                    combine_mfma<64><<<(cur + 63) / 64, 256, 0, stream>>>(
                        meanTc, T0c, Wc[1], bnS + 256, bnB + 256,
                        Tslice + (size_t)lo * WSL, WSL, 0, cur, c0);
            }
            if (WSL == 128)
                gmean_kernel<128><<<(NACC + 7) / 8, 256, 0, stream>>>(Tslice, WSL, ptrA, permR, meanbuf, H, c0, NACC, 0);
            else
                gmean_kernel<64><<<(NACC + 15) / 16, 256, 0, stream>>>(Tslice, WSL, ptrA, permR, meanbuf, H, c0, NACC, 0);
        }
        combine_mfma<256><<<gA, 256, 0, stream>>>(meanbuf, A1f, Wc[2], bnS + 512, bnB + 512, A0f, H, 0, NACC, 0);
        mlp_mfma<<<gM, 512, 0, stream>>>(A0f, sidx, ridx, tx_raw, W1F, b1, W2, b2, out, NM);
    }
}

// Round 16
// 938.678 us; speedup vs baseline: 1.0854x; 1.0854x over previous
//
#include <hip/hip_runtime.h>
#include <hip/hip_bf16.h>

#define H 256
#define NACC 100000
#define NTX  300000
#define NE   600000
#define NM   300000

typedef unsigned short u16;
typedef unsigned int u32;
typedef __bf16 bf16x8 __attribute__((ext_vector_type(8)));
typedef float f32x4 __attribute__((ext_vector_type(4)));

__device__ __forceinline__ float bf2f(u32 u) {
    union { u32 i; float f; } v; v.i = u << 16; return v.f;
}
__device__ __forceinline__ u16 f2bf(float f) {
    union { float f; u32 i; } v; v.f = f;
    u32 r = v.i + 0x7FFFu + ((v.i >> 16) & 1u);
    return (u16)(r >> 16);
}
__device__ __forceinline__ u32 pk2(float a, float b) {
    return (u32)f2bf(a) | ((u32)f2bf(b) << 16);
}
__device__ __forceinline__ void acc8(float* s, uint4 v) {
    s[0] += bf2f(v.x & 0xffff); s[1] += bf2f(v.x >> 16);
    s[2] += bf2f(v.y & 0xffff); s[3] += bf2f(v.y >> 16);
    s[4] += bf2f(v.z & 0xffff); s[5] += bf2f(v.z >> 16);
    s[6] += bf2f(v.w & 0xffff); s[7] += bf2f(v.w >> 16);
}

// ---------------- zero fill (no hipMemsetAsync: breaks graph capture) ----------------
__global__ void fillz_kernel(u32* __restrict__ p, long long n) {
    long long i = (long long)blockIdx.x * blockDim.x + threadIdx.x;
    long long st = (long long)gridDim.x * blockDim.x;
    for (; i < n; i += st) p[i] = 0u;
}

// ---------------- weight prep ----------------
__global__ void wcat_kernel(const float* __restrict__ Wl, const float* __restrict__ Wr,
                            u16* __restrict__ dst) {
    int c = blockIdx.x, t = threadIdx.x;
    dst[(size_t)c * 512 + t]       = f2bf(Wl[(size_t)c * 256 + t]);
    dst[(size_t)c * 512 + 256 + t] = f2bf(Wr[(size_t)c * 256 + t]);
}
// MFMA fragment-ordered concat, 3 configs in one launch (blockIdx.y = cfg)
__global__ void wcat_frag3_kernel(const float* __restrict__ Wl0, const float* __restrict__ Wr0,
                                  const float* __restrict__ Wl1, const float* __restrict__ Wr1,
                                  const float* __restrict__ Wl2, const float* __restrict__ Wr2,
                                  u16* __restrict__ d0, u16* __restrict__ d1, u16* __restrict__ d2) {
    int cfg = blockIdx.y;
    const float* Wl = (cfg == 0) ? Wl0 : (cfg == 1) ? Wl1 : Wl2;
    const float* Wr = (cfg == 0) ? Wr0 : (cfg == 1) ? Wr1 : Wr2;
    u16* dst = (cfg == 0) ? d0 : (cfg == 1) ? d1 : d2;
    int c = blockIdx.x, k = threadIdx.x;   // 256 x 512
    float v = (k < 256) ? Wl[(size_t)c * 256 + k] : Wr[(size_t)c * 256 + (k - 256)];
    int kstep = k >> 5, kg = (k & 31) >> 3, j = k & 7;
    dst[(size_t)((kstep * 16 + (c >> 4)) * 64 + kg * 16 + (c & 15)) * 8 + j] = f2bf(v);
}
__global__ void w1frag_kernel(const float* __restrict__ W1, u16* __restrict__ dst) {
    int c = blockIdx.x;
    for (int k = threadIdx.x; k < 544; k += 256) {
        float v = W1[(size_t)c * 544 + k];
        int kstep = k >> 5, kg = (k & 31) >> 3, j = k & 7;
        dst[(size_t)((kstep * 16 + (c >> 4)) * 64 + kg * 16 + (c & 15)) * 8 + j] = f2bf(v);
    }
}
// both projection-weight tables in one launch (blockIdx.y)
__global__ void wproj2_kernel(const float* __restrict__ Wa, const float* __restrict__ Wt,
                              u16* __restrict__ dA, u16* __restrict__ dT) {
    int c = blockIdx.x, t = threadIdx.x;   // 32 threads
    if (blockIdx.y == 0) dA[(size_t)c * 32 + t] = (t < 16) ? f2bf(Wa[(size_t)c * 16 + t]) : (u16)0;
    else                 dT[(size_t)c * 32 + t] = f2bf(Wt[(size_t)c * 32 + t]);
}
// all 3 BN-fold configs in one launch (blockIdx.x = cfg)
__global__ void bnprep3_kernel(const float* __restrict__ bl_ta, const float* __restrict__ bl_at,
                               const float* __restrict__ g_, const float* __restrict__ be_,
                               const float* __restrict__ m_, const float* __restrict__ v_,
                               float* __restrict__ S, float* __restrict__ B) {
    int cfg = blockIdx.x, c = threadIdx.x;
    const float* bl = (cfg == 0) ? bl_ta : (cfg == 1) ? bl_at : (bl_ta + 256);
    int po = (cfg == 2) ? 256 : 0;
    float s = g_[po + c] * rsqrtf(v_[po + c] + 1e-5f);
    S[cfg * 256 + c] = s;
    B[cfg * 256 + c] = (bl[c] - m_[po + c]) * s + be_[po + c];
}

// ---------------- MFMA projection (validated round 7) ------
template <int KK>
__launch_bounds__(256)
__global__ void proj_mfma(const float* __restrict__ x, const u16* __restrict__ Wb,
                          const float* __restrict__ b, u16* __restrict__ out, int N) {
    __shared__ __align__(16) u16 Af[8][64][8];
    __shared__ __align__(16) u16 Bf[16][64][8];
    int tid = threadIdx.x;
    int w = tid >> 6, lane = tid & 63;
    int row0 = blockIdx.x * 128;
    {
        int r = tid >> 1, h = tid & 1;
        int gr = row0 + r;
        int rt = r >> 4, rr = r & 15;
        uint4 p0 = make_uint4(0, 0, 0, 0), p1 = p0;
        if (gr < N && (KK == 32 || h == 0)) {
            const float* xp = x + (size_t)gr * KK + h * 16;
            float4 f0 = *(const float4*)(xp);
            float4 f1 = *(const float4*)(xp + 4);
            float4 f2 = *(const float4*)(xp + 8);
            float4 f3 = *(const float4*)(xp + 12);
            p0 = make_uint4(pk2(f0.x, f0.y), pk2(f0.z, f0.w), pk2(f1.x, f1.y), pk2(f1.z, f1.w));
            p1 = make_uint4(pk2(f2.x, f2.y), pk2(f2.z, f2.w), pk2(f3.x, f3.y), pk2(f3.z, f3.w));
        }
        int kg0 = 2 * h;
        *(uint4*)(&Af[rt][(kg0 * 16 + rr) ^ (kg0 << 2)][0]) = p0;
        *(uint4*)(&Af[rt][((kg0 + 1) * 16 + rr) ^ ((kg0 + 1) << 2)][0]) = p1;
    }
    {
        const u16* wp = Wb + (size_t)tid * 32;
#pragma unroll
        for (int q = 0; q < 4; ++q) {
            uint4 wv = *(const uint4*)(wp + q * 8);
            *(uint4*)(&Bf[tid >> 4][q * 16 + (tid & 15)][0]) = wv;
        }
    }
    __syncthreads();
    int arslot = lane ^ ((lane >> 4) << 2);
    f32x4 acc[8][4];
#pragma unroll
    for (int rt = 0; rt < 8; ++rt) {
        bf16x8 afr = *(const bf16x8*)(&Af[rt][arslot][0]);
#pragma unroll
        for (int ct = 0; ct < 4; ++ct) {
            bf16x8 bfr = *(const bf16x8*)(&Bf[w * 4 + ct][lane][0]);
            acc[rt][ct] = __builtin_amdgcn_mfma_f32_16x16x32_bf16(
                afr, bfr, (f32x4){0.f, 0.f, 0.f, 0.f}, 0, 0, 0);
        }
    }
    int rb = (lane >> 4) * 4, cc = lane & 15;
#pragma unroll
    for (int ct = 0; ct < 4; ++ct) {
        int cg = (w * 4 + ct) * 16 + cc;
        float bv = b[cg];
#pragma unroll
        for (int rt = 0; rt < 8; ++rt)
#pragma unroll
            for (int q = 0; q < 4; ++q) {
                int r = row0 + rt * 16 + rb + q;
                if (r < N)
                    out[(size_t)r * H + cg] = f2bf(fmaxf(acc[rt][ct][q] + bv, 0.0f));
            }
    }
}

// ---------------- CSR build (merged across both edge directions) ----------------
__global__ void count2_kernel(const int* __restrict__ dstS, const int* __restrict__ dstR, int E,
                              int* __restrict__ cntT, int* __restrict__ cntA) {
    int e = blockIdx.x * blockDim.x + threadIdx.x;
    if (e >= E) return;
    if (blockIdx.y == 0) atomicAdd(&cntT[dstS[e]], 1);
    else                 atomicAdd(&cntA[dstR[e]], 1);
}
__global__ void scan1_kernel(const int* __restrict__ cnt, int N,
                             int* __restrict__ loc, int* __restrict__ bsum) {
    __shared__ int sh[256];
    int b = blockIdx.x, t = threadIdx.x;
    int base = b * 1024 + t * 4;
    int v0 = (base + 0 < N) ? cnt[base + 0] : 0;
    int v1 = (base + 1 < N) ? cnt[base + 1] : 0;
    int v2 = (base + 2 < N) ? cnt[base + 2] : 0;
    int v3 = (base + 3 < N) ? cnt[base + 3] : 0;
    int s = v0 + v1 + v2 + v3;
    sh[t] = s;
    __syncthreads();
    for (int o = 1; o < 256; o <<= 1) {
        int y = (t >= o) ? sh[t - o] : 0;
        __syncthreads();
        sh[t] += y;
        __syncthreads();
    }
    int run = sh[t] - s;
    if (base + 0 < N) loc[base + 0] = run; run += v0;
    if (base + 1 < N) loc[base + 1] = run; run += v1;
    if (base + 2 < N) loc[base + 2] = run; run += v2;
    if (base + 3 < N) loc[base + 3] = run;
    if (t == 0) bsum[b] = sh[255];
}
__global__ void scan2_kernel(int* __restrict__ bsum, int nb) {
    __shared__ int sh[1024];
    int t = threadIdx.x;
    int v = (t < nb) ? bsum[t] : 0;
    sh[t] = v;
    __syncthreads();
    for (int o = 1; o < 1024; o <<= 1) {
        int y = (t >= o) ? sh[t - o] : 0;
        __syncthreads();
        sh[t] += y;
        __syncthreads();
    }
    if (t < nb) bsum[t] = sh[t] - v;
}
__global__ void scan3_kernel(int* __restrict__ ptr, const int* __restrict__ bsum,
                             int N, int total) {
    int i = blockIdx.x * blockDim.x + threadIdx.x;
    if (i < N) ptr[i] += bsum[i >> 10];
    else if (i == N) ptr[N] = total;
}
__global__ void fillcsr2_kernel(const int* __restrict__ srcS, const int* __restrict__ dstS,
                                const int* __restrict__ srcR, const int* __restrict__ dstR, int E,
                                const int* __restrict__ ptrT, int* __restrict__ curT, int* __restrict__ permS,
                                const int* __restrict__ ptrA, int* __restrict__ curA, int* __restrict__ permR) {
    int e = blockIdx.x * blockDim.x + threadIdx.x;
    if (e >= E) return;
    if (blockIdx.y == 0) {
        int d = dstS[e];
        permS[ptrT[d] + atomicAdd(&curT[d], 1)] = srcS[e];
    } else {
        int d = dstR[e];
        permR[ptrA[d] + atomicAdd(&curA[d], 1)] = srcR[e];
    }
}

// ---------------- gather-mean (kept for sliced fallback) ------------
template <int WS>
__launch_bounds__(256)
__global__ void gmean_kernel(const u16* __restrict__ feat, int fstride,
                             const int* __restrict__ ptr, const int* __restrict__ perm,
                             u16* __restrict__ out, int ostride, int c0,
                             int rows, int lo) {
    constexpr int LPD = WS / 4;
    constexpr int DPB = 256 / LPD;
    int g = threadIdx.x / LPD;
    int ln = threadIdx.x % LPD;
    int w = blockIdx.x * DPB + g;
    if (w >= rows) return;
    int d = lo + w;
    int e0 = ptr[d], e1 = ptr[d + 1];
    float a0 = 0.f, a1 = 0.f, a2 = 0.f, a3 = 0.f;
    for (int e = e0; e < e1; ++e) {
        int s = perm[e];
        uint2 v = *(const uint2*)(feat + (size_t)s * fstride + (ln << 2));
        a0 += bf2f(v.x & 0xffff); a1 += bf2f(v.x >> 16);
        a2 += bf2f(v.y & 0xffff); a3 += bf2f(v.y >> 16);
    }
    int deg = e1 - e0;
    float sc = (deg > 0) ? (1.0f / (float)deg) : 0.0f;
    uint2 pk;
    pk.x = pk2(a0 * sc, a1 * sc);
    pk.y = pk2(a2 * sc, a3 * sc);
    *(uint2*)(out + (size_t)w * ostride + c0 + (ln << 2)) = pk;
}

// ---------------- proj2 (kept for sliced fallback) ----------------
template <int K, int NC>
__launch_bounds__(256)
__global__ void proj2_kernel(const float* __restrict__ x, const float* __restrict__ W,
                             const float* __restrict__ b, u16* __restrict__ out,
                             int N, int c0, int ost) {
    __shared__ float xs[128][K + 4];
    constexpr int NG = 512 / NC;
    constexpr int RPT = 128 / NG;
    int tid = threadIdx.x;
    int row0 = blockIdx.x * 128;
    constexpr int NF4 = 128 * K / 4;
    for (int f = tid; f < NF4; f += 256) {
        int r = f / (K / 4), kq = (f % (K / 4)) * 4;
        int gr = row0 + r;
        float4 v = (gr < N) ? *(const float4*)(x + (size_t)gr * K + kq)
                            : make_float4(0.f, 0.f, 0.f, 0.f);
        *(float4*)&xs[r][kq] = v;
    }
    int lt2 = (tid % (NC / 2)) * 2;
    int g = tid / (NC / 2);
    float wa[K], wb[K];
    const float* wpa = W + (size_t)(c0 + lt2) * K;
#pragma unroll
    for (int k = 0; k < K; k += 4) {
        float4 va = *(const float4*)(wpa + k);
        float4 vb = *(const float4*)(wpa + K + k);
        wa[k] = va.x; wa[k + 1] = va.y; wa[k + 2] = va.z; wa[k + 3] = va.w;
        wb[k] = vb.x; wb[k + 1] = vb.y; wb[k + 2] = vb.z; wb[k + 3] = vb.w;
    }
    float b0 = b[c0 + lt2], b1 = b[c0 + lt2 + 1];
    __syncthreads();
#pragma unroll
    for (int rr = 0; rr < RPT; ++rr) {
        int r = g * RPT + rr;
        int gr = row0 + r;
        float a0 = b0, a1 = b1;
#pragma unroll
        for (int k = 0; k < K; k += 4) {
            float4 xv = *(const float4*)&xs[r][k];
            a0 += xv.x * wa[k] + xv.y * wa[k + 1] + xv.z * wa[k + 2] + xv.w * wa[k + 3];
            a1 += xv.x * wb[k] + xv.y * wb[k + 1] + xv.z * wb[k + 2] + xv.w * wb[k + 3];
        }
        if (gr < N) {
            u32 pk = (u32)f2bf(fmaxf(a0, 0.f)) | ((u32)f2bf(fmaxf(a1, 0.f)) << 16);
            *(u32*)(out + (size_t)gr * ost + lt2) = pk;
        }
    }
}

// ---------------- fused gather-mean + MFMA combine (round-11 validated v4) ----------------
// unroll2 phase-1, plain __launch_bounds__(512) (48 VGPR), plain cached loads.
__launch_bounds__(512)
__global__ void combine_gather(const u16* __restrict__ featG, const int* __restrict__ ptr,
                               const int* __restrict__ perm, const u16* __restrict__ xd,
                               const u16* __restrict__ WcF,
                               const float* __restrict__ bnS, const float* __restrict__ bnB,
                               u16* __restrict__ outF, int rows) {
    __shared__ __align__(16) u16 Am[8][4][64][8];   // 32 KB: mean half, fragment-ordered
    int tid = threadIdx.x;
    int w = tid >> 6, lane = tid & 63;
    int row0 = blockIdx.x * 64;

    // ---- phase 1: gather-mean, 8 threads per row (32 cols each), unroll2 ----
    {
        int r = tid >> 3, g = tid & 7;      // r 0..63, colgroup g 0..7
        int grow = row0 + r;
        float s[32];
#pragma unroll
        for (int i = 0; i < 32; ++i) s[i] = 0.0f;
        float inv = 0.0f;
        if (grow < rows) {
            int e0 = ptr[grow], e1 = ptr[grow + 1];
            int dg = e1 - e0;
            inv = (dg > 0) ? 1.0f / (float)dg : 0.0f;
            int e = e0;
            for (; e + 1 < e1; e += 2) {
                int n0 = perm[e], n1 = perm[e + 1];
                const u16* p0 = featG + (size_t)n0 * H + g * 32;
                const u16* p1 = featG + (size_t)n1 * H + g * 32;
#pragma unroll
                for (int q = 0; q < 4; ++q) {
                    uint4 v0 = *(const uint4*)(p0 + q * 8);
                    uint4 v1 = *(const uint4*)(p1 + q * 8);
                    acc8(s + q * 8, v0);
                    acc8(s + q * 8, v1);
                }
            }
            if (e < e1) {
                int n0 = perm[e];
                const u16* p0 = featG + (size_t)n0 * H + g * 32;
#pragma unroll
                for (int q = 0; q < 4; ++q)
                    acc8(s + q * 8, *(const uint4*)(p0 + q * 8));
            }
        }
        int rt = r >> 4, rr = r & 15;
#pragma unroll
        for (int q = 0; q < 4; ++q) {
            int kgg = g * 4 + q;                 // global kgroup 0..31
            int kbs = kgg >> 2, akg = kgg & 3;   // kb-step, in-step group
            uint4 pv;
            pv.x = pk2(s[q * 8 + 0] * inv, s[q * 8 + 1] * inv);
            pv.y = pk2(s[q * 8 + 2] * inv, s[q * 8 + 3] * inv);
            pv.z = pk2(s[q * 8 + 4] * inv, s[q * 8 + 5] * inv);
            pv.w = pk2(s[q * 8 + 6] * inv, s[q * 8 + 7] * inv);
            *(uint4*)(&Am[kbs][rt][(akg * 16 + rr) ^ (akg << 2)][0]) = pv;
        }
    }
    __syncthreads();

    // ---- phase 2: barrier-free K-loop, wave w owns col-tiles w*2, w*2+1 ----
    int arslot = lane ^ ((lane >> 4) << 2);
    const u16* xrow[4];
#pragma unroll
    for (int rt = 0; rt < 4; ++rt) {
        int r = row0 + rt * 16 + (lane & 15);
        if (r > rows - 1) r = rows - 1;
        xrow[rt] = xd + (size_t)r * H + (lane >> 4) * 8;
    }
    const u16* wb = WcF + (size_t)lane * 8;

    f32x4 acc[4][2];
#pragma unroll
    for (int i = 0; i < 4; ++i) {
        acc[i][0] = (f32x4){0.f, 0.f, 0.f, 0.f};
        acc[i][1] = (f32x4){0.f, 0.f, 0.f, 0.f};
    }
#pragma unroll
    for (int ks = 0; ks < 8; ++ks) {        // kb 0..255: A from Am
        bf16x8 afr[4];
#pragma unroll
        for (int rt = 0; rt < 4; ++rt)
            afr[rt] = *(const bf16x8*)(&Am[ks][rt][arslot][0]);
#pragma unroll
        for (int j = 0; j < 2; ++j) {
            bf16x8 bfr = *(const bf16x8*)(wb + (size_t)(ks * 16 + w * 2 + j) * 512);
#pragma unroll
            for (int rt = 0; rt < 4; ++rt)
                acc[rt][j] = __builtin_amdgcn_mfma_f32_16x16x32_bf16(afr[rt], bfr, acc[rt][j], 0, 0, 0);
        }
    }
#pragma unroll
    for (int ks = 8; ks < 16; ++ks) {       // kb 256..511: A direct from xd
        bf16x8 afr[4];
#pragma unroll
        for (int rt = 0; rt < 4; ++rt)
            afr[rt] = *(const bf16x8*)(xrow[rt] + (ks - 8) * 32);
#pragma unroll
        for (int j = 0; j < 2; ++j) {
            bf16x8 bfr = *(const bf16x8*)(wb + (size_t)(ks * 16 + w * 2 + j) * 512);
#pragma unroll
            for (int rt = 0; rt < 4; ++rt)
                acc[rt][j] = __builtin_amdgcn_mfma_f32_16x16x32_bf16(afr[rt], bfr, acc[rt][j], 0, 0, 0);
        }
    }
    __syncthreads();   // in-place safety: all xd reads done before any store
    int rb = (lane >> 4) * 4, cc = lane & 15;
#pragma unroll
    for (int j = 0; j < 2; ++j) {
        int cg = (w * 2 + j) * 16 + cc;
        float s = bnS[cg], sh = bnB[cg];
#pragma unroll
        for (int rt = 0; rt < 4; ++rt)
#pragma unroll
            for (int q = 0; q < 4; ++q) {
                int r = row0 + rt * 16 + rb + q;
                if (r < rows)
                    outF[(size_t)r * H + cg] = f2bf(fmaxf(acc[rt][j][q] * s + sh, 0.0f));
            }
    }
}

// ---------------- MFMA SAGE combine (kept for sliced fallback, plain Wcat) ----------------
template <int COLS>
__launch_bounds__(256)
__global__ void combine_mfma(const u16* __restrict__ mean_, const u16* __restrict__ xd,
                             const u16* __restrict__ Wcat,
                             const float* __restrict__ bnS, const float* __restrict__ bnB,
                             u16* __restrict__ outF, int ostride, int out_c0,
                             int rows, int c0) {
    constexpr int NCT = COLS / 16;
    constexpr int CTW = NCT / 4;
    constexpr int PPT = (COLS * 4) / 256;
    __shared__ __align__(16) u16 Af[4][64][8];
    __shared__ __align__(16) u16 Bf[NCT][64][8];
    int tid = threadIdx.x;
    int w = tid >> 6, lane = tid & 63;
    int row0 = blockIdx.x * 64;
    int arow = tid >> 2, akg = tid & 3;
    bool arok = (row0 + arow) < rows;
    const u16* am = mean_ + (size_t)(row0 + arow) * H;
    const u16* ax = xd + (size_t)(row0 + arow) * H;
    int awslot = (akg * 16 + (arow & 15)) ^ (akg << 2);
    int arslot = lane ^ ((lane >> 4) << 2);
    int bc = tid % COLS;
    int bkg0 = (tid / COLS) * PPT;
    const u16* wp0 = Wcat + (size_t)(c0 + bc) * 512 + bkg0 * 8;

    f32x4 acc[4][CTW];
#pragma unroll
    for (int i = 0; i < 4; ++i)
#pragma unroll
        for (int j = 0; j < CTW; ++j) acc[i][j] = (f32x4){0.f, 0.f, 0.f, 0.f};

    for (int kb = 0; kb < 512; kb += 32) {
        uint4 av = make_uint4(0, 0, 0, 0);
        if (arok) {
            int kg = kb + akg * 8;
            av = (kg < 256) ? *(const uint4*)(am + kg) : *(const uint4*)(ax + (kg - 256));
        }
        *(uint4*)(&Af[arow >> 4][awslot][0]) = av;
#pragma unroll
        for (int q = 0; q < PPT; ++q) {
            uint4 wv = *(const uint4*)(wp0 + kb + q * 8);
            *(uint4*)(&Bf[bc >> 4][(bkg0 + q) * 16 + (bc & 15)][0]) = wv;
        }
        __syncthreads();
        bf16x8 afr[4];
#pragma unroll
        for (int rt = 0; rt < 4; ++rt)
            afr[rt] = *(const bf16x8*)(&Af[rt][arslot][0]);
#pragma unroll
        for (int ctl = 0; ctl < CTW; ++ctl) {
            bf16x8 b = *(const bf16x8*)(&Bf[w * CTW + ctl][lane][0]);
#pragma unroll
            for (int rt = 0; rt < 4; ++rt)
                acc[rt][ctl] = __builtin_amdgcn_mfma_f32_16x16x32_bf16(afr[rt], b, acc[rt][ctl], 0, 0, 0);
        }
        __syncthreads();
    }
    int rb = (lane >> 4) * 4;
    int ccol = lane & 15;
#pragma unroll
    for (int ctl = 0; ctl < CTW; ++ctl) {
        int clocal = (w * CTW + ctl) * 16 + ccol;
        int cg = c0 + clocal;
        float s = bnS[cg], sh = bnB[cg];
#pragma unroll
        for (int rt = 0; rt < 4; ++rt) {
#pragma unroll
            for (int q = 0; q < 4; ++q) {
                int r = row0 + rt * 16 + rb + q;
                if (r < rows)
                    outF[(size_t)r * ostride + out_c0 + clocal] = f2bf(fmaxf(acc[rt][ctl][q] * s + sh, 0.0f));
            }
        }
    }
}

// ---------------- MFMA edge-MLP head v4 (round-11 validated) ------
__launch_bounds__(512)
__global__ void mlp_mfma(const u16* __restrict__ accF, const int* __restrict__ sidx,
                         const int* __restrict__ ridx, const float* __restrict__ txr,
                         const u16* __restrict__ W1F, const float* __restrict__ b1,
                         const float* __restrict__ W2, const float* __restrict__ b2,
                         float* __restrict__ out, int M) {
    __shared__ __align__(16) u16 Af[4][64][8];
    __shared__ float red[8][64];
    int tid = threadIdx.x;
    int w = tid >> 6, lane = tid & 63;
    int row0 = blockIdx.x * 64;
    int sr = tid >> 3, sg = tid & 7;
    int grow = row0 + sr;
    int gcl = (grow > M - 1) ? (M - 1) : grow;
    const u16* srow_s = accF + (size_t)sidx[gcl] * H + sg * 4;
    const u16* srow_r = accF + (size_t)ridx[gcl] * H + sg * 4;
    const float* tp = txr + (size_t)gcl * 32 + sg * 4;
    int rt_s = sr >> 4, rr_s = sr & 15;
    int akg = sg >> 1, hh = (sg & 1) * 4;
    u16* wslot = &Af[rt_s][(akg * 16 + rr_s) ^ (akg << 2)][hh];

    auto stage_load = [&](int ks) -> uint2 {
        if (ks < 8)  return *(const uint2*)(srow_s + ks * 32);
        if (ks < 16) return *(const uint2*)(srow_r + (ks - 8) * 32);
        float4 f = *(const float4*)tp;
        uint2 r;
        r.x = pk2(f.x, f.y); r.y = pk2(f.z, f.w);
        return r;
    };

    int arslot = lane ^ ((lane >> 4) << 2);
    const u16* wbs = W1F + (size_t)lane * 8;

    f32x4 acc[4][2];
#pragma unroll
    for (int i = 0; i < 4; ++i) {
        acc[i][0] = (f32x4){0.f, 0.f, 0.f, 0.f};
        acc[i][1] = (f32x4){0.f, 0.f, 0.f, 0.f};
    }

    uint2 reg = stage_load(0);
#pragma unroll
    for (int ks = 0; ks < 17; ++ks) {
        __syncthreads();
        *(uint2*)wslot = reg;
        __syncthreads();
        if (ks < 16) reg = stage_load(ks + 1);
        bf16x8 afr[4];
#pragma unroll
        for (int rt = 0; rt < 4; ++rt)
            afr[rt] = *(const bf16x8*)(&Af[rt][arslot][0]);
#pragma unroll
        for (int j = 0; j < 2; ++j) {
            bf16x8 bfr = *(const bf16x8*)(wbs + (size_t)(ks * 16 + w * 2 + j) * 512);
#pragma unroll
            for (int rt = 0; rt < 4; ++rt)
                acc[rt][j] = __builtin_amdgcn_mfma_f32_16x16x32_bf16(afr[rt], bfr, acc[rt][j], 0, 0, 0);
        }
    }
    float part[4][4];
#pragma unroll
    for (int rt = 0; rt < 4; ++rt)
#pragma unroll
        for (int q = 0; q < 4; ++q) part[rt][q] = 0.0f;
#pragma unroll
    for (int j = 0; j < 2; ++j) {
        int cg = (w * 2 + j) * 16 + (lane & 15);
        float b1v = b1[cg], w2v = W2[cg];
#pragma unroll
        for (int rt = 0; rt < 4; ++rt)
#pragma unroll
            for (int q = 0; q < 4; ++q)
                part[rt][q] += fmaxf(acc[rt][j][q] + b1v, 0.0f) * w2v;
    }
    int rb = (lane >> 4) * 4;
#pragma unroll
    for (int rt = 0; rt < 4; ++rt)
#pragma unroll
        for (int q = 0; q < 4; ++q) {
            float p = part[rt][q];
            p += __shfl_xor(p, 1);
            p += __shfl_xor(p, 2);
            p += __shfl_xor(p, 4);
            p += __shfl_xor(p, 8);
            if ((lane & 15) == 0) red[w][rt * 16 + rb + q] = p;
        }
    __syncthreads();
    if (tid < 64) {
        int r = row0 + tid;
        if (r < M)
            out[r] = red[0][tid] + red[1][tid] + red[2][tid] + red[3][tid]
                   + red[4][tid] + red[5][tid] + red[6][tid] + red[7][tid] + b2[0];
    }
}

// ---------------- host ----------------
static inline void fz(void* p, size_t bytes, hipStream_t s) {
    long long n = (long long)(bytes >> 2);
    int g = (int)(((n + 255) / 256 < 2048) ? (n + 255) / 256 : 2048);
    fillz_kernel<<<g, 256, 0, s>>>((u32*)p, n);
}
static inline size_t al256(size_t x) { return (x + 255) & ~(size_t)255; }

extern "C" void kernel_launch(void* const* d_in, const int* in_sizes, int n_in,
                              void* d_out, int out_size, void* d_ws, size_t ws_size,
                              hipStream_t stream) {
    const float* x_acc  = (const float*)d_in[0];
    const float* x_tx   = (const float*)d_in[1];
    const float* tx_raw = (const float*)d_in[2];
    const int* ei_sends = (const int*)d_in[3];
    const int* ei_recv  = (const int*)d_in[4];
    const int* sidx     = (const int*)d_in[5];
    const int* ridx     = (const int*)d_in[6];
    const float* W_acc  = (const float*)d_in[7];
    const float* b_acc  = (const float*)d_in[8];
    const float* W_tx   = (const float*)d_in[9];
    const float* b_tx   = (const float*)d_in[10];
    const float* Wl_at  = (const float*)d_in[11];
    const float* bl_at  = (const float*)d_in[12];
    const float* Wr_at  = (const float*)d_in[13];
    const float* Wl_ta  = (const float*)d_in[14];
    const float* bl_ta  = (const float*)d_in[15];
    const float* Wr_ta  = (const float*)d_in[16];
    const float* bng    = (const float*)d_in[17];
    const float* bnb    = (const float*)d_in[18];
    const float* bnm    = (const float*)d_in[19];
    const float* bnv    = (const float*)d_in[20];
    const float* W1     = (const float*)d_in[21];
    const float* b1     = (const float*)d_in[22];
    const float* W2     = (const float*)d_in[23];
    const float* b2     = (const float*)d_in[24];
    float* out = (float*)d_out;

    const size_t szFeatA = (size_t)NACC * H * 2;
    const size_t szFeatT = (size_t)NTX * H * 2;
    const size_t szCSR = al256((NTX + 1) * 4) + al256((NACC + 1) * 4) + al256(4096)
                       + al256((NTX + 1) * 4) + al256((NACC + 1) * 4)
                       + 2 * al256((size_t)NE * 4);
    const size_t szW = 3 * al256(256 * 512 * 2) + 3 * al256(16 * 16 * 64 * 8 * 2)
                     + al256(17 * 16 * 64 * 8 * 2)
                     + 2 * al256(3 * 256 * 4) + 2 * al256(256 * 32 * 2);

    size_t needF = szCSR + szW + 2 * al256(szFeatA) + al256(szFeatT) + 65536;
    auto needS = [&](int S, int CC) {
        return 3 * al256(szFeatA) + szCSR + szW + 2 * al256((size_t)CC * H * 2)
             + al256((size_t)NTX * (H / S) * 2) + 65536;
    };
    int plan, S = 2, CC = 16384;
    if (needF <= ws_size)                { plan = 0; }
    else if (needS(2, 16384) <= ws_size) { plan = 1; S = 2; CC = 16384; }
    else if (needS(4, 16384) <= ws_size) { plan = 1; S = 4; CC = 16384; }
    else                                 { plan = 1; S = 4; CC = 2048; }

    char* wsp = (char*)d_ws;
    size_t off = 0;
    auto alloc = [&](size_t bytes) -> void* {
        void* p = wsp + off;
        off = al256(off + bytes);
        return p;
    };
    // cntT and cntA adjacent so one fz covers both
    int* cntT  = (int*)alloc((NTX + 1) * 4);
    int* cntA  = (int*)alloc((NACC + 1) * 4);
    int* bsum  = (int*)alloc(4096);
    int* ptrT  = (int*)alloc((NTX + 1) * 4);
    int* ptrA  = (int*)alloc((NACC + 1) * 4);
    int* permS = (int*)alloc((size_t)NE * 4);
    int* permR = (int*)alloc((size_t)NE * 4);
    u16* Wc[3];
    Wc[0] = (u16*)alloc(256 * 512 * 2);
    Wc[1] = (u16*)alloc(256 * 512 * 2);
    Wc[2] = (u16*)alloc(256 * 512 * 2);
    u16* WcF[3];
    WcF[0] = (u16*)alloc(16 * 16 * 64 * 8 * 2);
    WcF[1] = (u16*)alloc(16 * 16 * 64 * 8 * 2);
    WcF[2] = (u16*)alloc(16 * 16 * 64 * 8 * 2);
    u16* W1F = (u16*)alloc(17 * 16 * 64 * 8 * 2);
    float* bnS = (float*)alloc(3 * 256 * 4);
    float* bnB = (float*)alloc(3 * 256 * 4);
    u16* WbA = (u16*)alloc(256 * 32 * 2);
    u16* WbT = (u16*)alloc(256 * 32 * 2);
    u16* A0f = (u16*)alloc(szFeatA);
    u16* A1f = (u16*)alloc(szFeatA);

    const size_t cntBytes = al256((NTX + 1) * 4) + al256((NACC + 1) * 4);

    // ---- weight prep (merged launches) ----
    wcat_frag3_kernel<<<dim3(256, 3), 512, 0, stream>>>(
        Wl_ta, Wr_ta, Wl_at, Wr_at, Wl_ta + H * H, Wr_ta + H * H, WcF[0], WcF[1], WcF[2]);
    w1frag_kernel<<<256, 256, 0, stream>>>(W1, W1F);
    wproj2_kernel<<<dim3(256, 2), 32, 0, stream>>>(W_acc, W_tx, WbA, WbT);
    bnprep3_kernel<<<3, 256, 0, stream>>>(bl_ta, bl_at, bng, bnb, bnm, bnv, bnS, bnB);

    // ---- CSR build, both directions merged ----
    const int EG = (NE + 255) / 256;
    const int nbT = (NTX + 1023) / 1024, nbA = (NACC + 1023) / 1024;
    fz(cntT, cntBytes, stream);
    count2_kernel<<<dim3(EG, 2), 256, 0, stream>>>(ei_sends + NE, ei_recv + NE, NE, cntT, cntA);
    scan1_kernel<<<nbT, 256, 0, stream>>>(cntT, NTX, ptrT, bsum);
    scan2_kernel<<<1, 1024, 0, stream>>>(bsum, nbT);
    scan3_kernel<<<(NTX + 256) / 256 + 1, 256, 0, stream>>>(ptrT, bsum, NTX, NE);
    scan1_kernel<<<nbA, 256, 0, stream>>>(cntA, NACC, ptrA, bsum);
    scan2_kernel<<<1, 1024, 0, stream>>>(bsum, nbA);
    scan3_kernel<<<(NACC + 256) / 256 + 1, 256, 0, stream>>>(ptrA, bsum, NACC, NE);
    fz(cntT, cntBytes, stream);
    fillcsr2_kernel<<<dim3(EG, 2), 256, 0, stream>>>(
        ei_sends, ei_sends + NE, ei_recv, ei_recv + NE, NE,
        ptrT, cntT, permS, ptrA, cntA, permR);

    // ---- acc projection (MFMA) ----
    proj_mfma<16><<<(NACC + 127) / 128, 256, 0, stream>>>(x_acc, WbA, b_acc, A0f, NACC);

    const int gA = (NACC + 63) / 64, gM = (NM + 63) / 64;

    if (plan == 0) {
        // ======== PLAN FULL (round-11 validated kernel set) ========
        u16* T = (u16*)alloc(szFeatT);
        proj_mfma<32><<<(NTX + 127) / 128, 256, 0, stream>>>(x_tx, WbT, b_tx, T, NTX);
        // L0 acc: gather T0 over recv, root A0f -> A1f (must precede in-place T overwrite)
        combine_gather<<<gA, 512, 0, stream>>>(T, ptrA, permR, A0f, WcF[0], bnS, bnB, A1f, NACC);
        // L0 tx: gather A0f over sends, root T0 -> T1 in place
        combine_gather<<<(NTX + 63) / 64, 512, 0, stream>>>(A0f, ptrT, permS, T, WcF[1],
                                                            bnS + 256, bnB + 256, T, NTX);
        // L1 acc: gather T1 over recv, root A1f -> A2 (reuse A0f)
        combine_gather<<<gA, 512, 0, stream>>>(T, ptrA, permR, A1f, WcF[2],
                                               bnS + 512, bnB + 512, A0f, NACC);
        mlp_mfma<<<gM, 512, 0, stream>>>(A0f, sidx, ridx, tx_raw, W1F, b1, W2, b2, out, NM);
    } else {
        // ======== PLAN SLICED (validated fallback) ========
        wcat_kernel<<<256, 256, 0, stream>>>(Wl_ta, Wr_ta, Wc[0]);
        wcat_kernel<<<256, 256, 0, stream>>>(Wl_at, Wr_at, Wc[1]);
        wcat_kernel<<<256, 256, 0, stream>>>(Wl_ta + H * H, Wr_ta + H * H, Wc[2]);
        u16* meanbuf = (u16*)alloc(szFeatA);
        u16* T0c     = (u16*)alloc((size_t)CC * H * 2);
        u16* meanTc  = (u16*)alloc((size_t)CC * H * 2);
        const int WSL = H / S;
        u16* Tslice  = (u16*)alloc((size_t)NTX * WSL * 2);

        for (int s = 0; s < S; ++s) {
            int c0 = s * WSL;
            if (WSL == 128)
                proj2_kernel<32, 128><<<(NTX + 127) / 128, 256, 0, stream>>>(x_tx, W_tx, b_tx, Tslice, NTX, c0, WSL);
            else
                proj2_kernel<32, 64><<<(NTX + 127) / 128, 256, 0, stream>>>(x_tx, W_tx, b_tx, Tslice, NTX, c0, WSL);
            if (WSL == 128)
                gmean_kernel<128><<<(NACC + 7) / 8, 256, 0, stream>>>(Tslice, WSL, ptrA, permR, meanbuf, H, c0, NACC, 0);
            else
                gmean_kernel<64><<<(NACC + 15) / 16, 256, 0, stream>>>(Tslice, WSL, ptrA, permR, meanbuf, H, c0, NACC, 0);
        }
        combine_mfma<256><<<gA, 256, 0, stream>>>(meanbuf, A0f, Wc[0], bnS, bnB, A1f, H, 0, NACC, 0);
        for (int s = 0; s < S; ++s) {
            int c0 = s * WSL;
            for (int lo = 0; lo < NTX; lo += CC) {
                int cur = (NTX - lo < CC) ? (NTX - lo) : CC;
                proj2_kernel<32, 256><<<(cur + 127) / 128, 256, 0, stream>>>(x_tx + (size_t)lo * 32, W_tx, b_tx, T0c, cur, 0, H);
                gmean_kernel<256><<<(cur + 3) / 4, 256, 0, stream>>>(A0f, H, ptrT, permS, meanTc, H, 0, cur, lo);
                if (WSL == 128)
                    combine_mfma<128><<<(cur + 63) / 64, 256, 0, stream>>>(
                        meanTc, T0c, Wc[1], bnS + 256, bnB + 256,
                        Tslice + (size_t)lo * WSL, WSL, 0, cur, c0);
                else
                    combine_mfma<64><<<(cur + 63) / 64, 256, 0, stream>>>(
                        meanTc, T0c, Wc[1], bnS + 256, bnB + 256,
                        Tslice + (size_t)lo * WSL, WSL, 0, cur, c0);
            }
            if (WSL == 128)
                gmean_kernel<128><<<(NACC + 7) / 8, 256, 0, stream>>>(Tslice, WSL, ptrA, permR, meanbuf, H, c0, NACC, 0);
            else
                gmean_kernel<64><<<(NACC + 15) / 16, 256, 0, stream>>>(Tslice, WSL, ptrA, permR, meanbuf, H, c0, NACC, 0);
        }
        combine_mfma<256><<<gA, 256, 0, stream>>>(meanbuf, A1f, Wc[2], bnS + 512, bnB + 512, A0f, H, 0, NACC, 0);
        mlp_mfma<<<gM, 512, 0, stream>>>(A0f, sidx, ridx, tx_raw, W1F, b1, W2, b2, out, NM);
    }
}